// Round 5
// baseline (576.432 us; speedup 1.0000x reference)
//
#include <hip/hip_runtime.h>

// Model: e = maxpool_L(relu(x @ Wc^T + bc)); feat = [e1-e2, e1*e2];
//        h = tanh(feat @ W1^T + b1); out = h @ W2^T + b2   (all fp32 I/O)
// Sizes: B=2048, L=64, D=300, C=512, H=2048, O=1.
// R4 lesson: latency-bound — B-frag loads serialized inside the MFMA loop
// (no reg headroom to hoist; 2 waves/SIMD can't hide ~200cyc L2 latency).
// R5: explicit distance-1 software pipeline (prefetch next ks A+B frags into
// rotation regs), kc-major/nt-inner operand layout (one base + imm offsets),
// fc1 retiled 4x4 (16 MFMA / 8 loads). Reg budget kept <=256 (2 waves/SIMD).

#define B_SZ 2048
#define L_SZ 64
#define D_SZ 300
#define C_SZ 512
#define H_SZ 2048
#define KPAD 320      // D padded to 32
#define NKC 40        // KPAD/8 kchunks (encode)
#define LDSPITCH 328  // x-tile LDS pitch

typedef __bf16 bf16x8 __attribute__((ext_vector_type(8)));
typedef float f32x4 __attribute__((ext_vector_type(4)));

__device__ __forceinline__ unsigned short f2bf(float f) {
  unsigned int u = __float_as_uint(f);
  u += 0x7fffu + ((u >> 16) & 1u);   // RNE
  return (unsigned short)(u >> 16);
}

// ---- kernel 0: swizzled bf16 weights, kc-major / tile / lane16 / 8elem.
// WcSwz[kc<40][ctile<32][l16][8]   (zero-pad k>=300)
// W1Swz[kc<128][jtile<128][l16][8]
__global__ __launch_bounds__(256)
void convert_kernel(const float* __restrict__ Wc, const float* __restrict__ W1,
                    unsigned short* __restrict__ WcSwz, unsigned short* __restrict__ W1Swz) {
  int id = blockIdx.x * 256 + threadIdx.x;
  if (id < C_SZ * NKC) {                      // (c, kc), kc inner
    int c = id / NKC, kc = id - c * NKC;
    unsigned short tmp[8];
    #pragma unroll
    for (int i = 0; i < 8; ++i) {
      int k = kc * 8 + i;
      tmp[i] = (k < D_SZ) ? f2bf(Wc[c * D_SZ + k]) : (unsigned short)0;
    }
    unsigned short* dst = WcSwz + (((kc * 32 + (c >> 4)) * 16) + (c & 15)) * 8;
    *reinterpret_cast<uint4*>(dst) = *reinterpret_cast<uint4*>(tmp);
    return;
  }
  id -= C_SZ * NKC;
  if (id < H_SZ * 128) {                      // (j, kc), kc inner
    int j = id >> 7, kc = id & 127;
    const float* src = W1 + (size_t)j * 1024 + kc * 8;
    unsigned short tmp[8];
    #pragma unroll
    for (int i = 0; i < 8; ++i) tmp[i] = f2bf(src[i]);
    unsigned short* dst = W1Swz + (((kc * 128 + (j >> 4)) * 16) + (j & 15)) * 8;
    *reinterpret_cast<uint4*>(dst) = *reinterpret_cast<uint4*>(tmp);
  }
}

// ---- kernel 1: encode. One block per (batch, z). M=64, N=512, K=320.
// Software-pipelined: prefetch ks+1 A(LDS)/B(global) frags during ks MFMAs.
__global__ __launch_bounds__(256, 2)
void encode_kernel(const float* __restrict__ x1, const float* __restrict__ x2,
                   const unsigned short* __restrict__ WcSwz,
                   const float* __restrict__ bc, float* __restrict__ e) {
  const int b = blockIdx.x, z = blockIdx.y;
  const float* __restrict__ x = (z ? x2 : x1) + (size_t)b * (L_SZ * D_SZ);
  __shared__ unsigned short xs[L_SZ * LDSPITCH];  // 41,984 B
  const int tid = threadIdx.x;

  const float4* __restrict__ xv = reinterpret_cast<const float4*>(x);
  for (int i = tid; i < (L_SZ * D_SZ / 4); i += 256) {
    float4 v = xv[i];
    int word = i / 75, col = (i - word * 75) * 4;
    unsigned int lo = (unsigned int)f2bf(v.x) | ((unsigned int)f2bf(v.y) << 16);
    unsigned int hi = (unsigned int)f2bf(v.z) | ((unsigned int)f2bf(v.w) << 16);
    *reinterpret_cast<uint2*>(&xs[word * LDSPITCH + col]) = make_uint2(lo, hi);
  }
  for (int i = tid; i < L_SZ * (KPAD - D_SZ); i += 256) {  // zero K-pad cols
    int word = i / 20, c = D_SZ + (i - word * 20);
    xs[word * LDSPITCH + c] = 0;
  }
  __syncthreads();

  const int wave = tid >> 6, lane = tid & 63;
  const int l16 = lane & 15, quad = lane >> 4;

  f32x4 acc[4][8];
  #pragma unroll
  for (int mt = 0; mt < 4; ++mt)
    #pragma unroll
    for (int nt = 0; nt < 8; ++nt)
      #pragma unroll
      for (int r = 0; r < 4; ++r) acc[mt][nt][r] = 0.f;

  // B base for (ks, nt): WcSwz + (((ks*4+quad)*32 + wave*8 + nt)*16 + l16)*8
  // A base for (ks, mt): xs[(mt*16+l16)*LDSPITCH + ks*32 + quad*8]
  bf16x8 a[4], an[4], bw[8], bn[8];
  #pragma unroll
  for (int mt = 0; mt < 4; ++mt)
    a[mt] = *reinterpret_cast<const bf16x8*>(&xs[(mt * 16 + l16) * LDSPITCH + quad * 8]);
  #pragma unroll
  for (int nt = 0; nt < 8; ++nt)
    bw[nt] = *reinterpret_cast<const bf16x8*>(
        WcSwz + (((quad * 32) + wave * 8 + nt) * 16 + l16) * 8);

  #pragma unroll
  for (int ks = 0; ks < KPAD / 32; ++ks) {
    if (ks < KPAD / 32 - 1) {  // prefetch ks+1
      #pragma unroll
      for (int mt = 0; mt < 4; ++mt)
        an[mt] = *reinterpret_cast<const bf16x8*>(
            &xs[(mt * 16 + l16) * LDSPITCH + (ks + 1) * 32 + quad * 8]);
      #pragma unroll
      for (int nt = 0; nt < 8; ++nt)
        bn[nt] = *reinterpret_cast<const bf16x8*>(
            WcSwz + ((((ks + 1) * 4 + quad) * 32 + wave * 8 + nt) * 16 + l16) * 8);
    }
    #pragma unroll
    for (int nt = 0; nt < 8; ++nt)
      #pragma unroll
      for (int mt = 0; mt < 4; ++mt)
        acc[mt][nt] = __builtin_amdgcn_mfma_f32_16x16x32_bf16(a[mt], bw[nt], acc[mt][nt], 0, 0, 0);
    if (ks < KPAD / 32 - 1) {  // rotate (SSA-renamed, zero cost)
      #pragma unroll
      for (int mt = 0; mt < 4; ++mt) a[mt] = an[mt];
      #pragma unroll
      for (int nt = 0; nt < 8; ++nt) bw[nt] = bn[nt];
    }
  }

  // +bias, relu, max over the 64 words (C/D: row=quad*4+r, col=l16)
  #pragma unroll
  for (int nt = 0; nt < 8; ++nt) {
    int c = wave * 128 + nt * 16 + l16;
    float bias = bc[c];
    float v = 0.f;  // relu floor
    #pragma unroll
    for (int mt = 0; mt < 4; ++mt)
      #pragma unroll
      for (int r = 0; r < 4; ++r)
        v = fmaxf(v, acc[mt][nt][r] + bias);
    v = fmaxf(v, __shfl_xor(v, 16));
    v = fmaxf(v, __shfl_xor(v, 32));
    if (quad == 0)
      e[((size_t)z * B_SZ + b) * C_SZ + c] = v;
  }
}

// ---- kernel 2: featSwz[kc<128][btile<128][l16][8]
__global__ __launch_bounds__(256)
void feat_kernel(const float* __restrict__ e, unsigned short* __restrict__ featSwz) {
  int id = blockIdx.x * 256 + threadIdx.x;   // (b, kc), kc inner
  if (id >= B_SZ * 128) return;
  int b = id >> 7, kc = id & 127;
  unsigned short tmp[8];
  #pragma unroll
  for (int i = 0; i < 8; ++i) {
    int k = kc * 8 + i, c = k & 511;
    float a = e[(size_t)b * C_SZ + c];
    float bb = e[(size_t)B_SZ * C_SZ + (size_t)b * C_SZ + c];
    tmp[i] = f2bf((k < C_SZ) ? (a - bb) : (a * bb));
  }
  unsigned short* dst = featSwz + (((kc * 128 + (b >> 4)) * 16) + (b & 15)) * 8;
  *reinterpret_cast<uint4*>(dst) = *reinterpret_cast<uint4*>(tmp);
}

// ---- kernel 3: fc1+fc2 fused, 4x4 tiles, pipelined. Block: M=64 x N=256.
// partial[slice<32][b] = sum over this wave's 64 j-cols of tanh(pre)*W2[j].
__global__ __launch_bounds__(256, 2)
void fc1_kernel(const unsigned short* __restrict__ featSwz,
                const unsigned short* __restrict__ W1Swz,
                const float* __restrict__ b1, const float* __restrict__ W2,
                float* __restrict__ partial) {
  const int tid = threadIdx.x;
  const int wave = tid >> 6, lane = tid & 63;
  const int l16 = lane & 15, quad = lane >> 4;
  const int mtile = blockIdx.x * 4;             // a-tiles mtile+mt
  const int ntile = blockIdx.y * 16 + wave * 4; // b-tiles ntile+nt

  f32x4 acc[4][4];
  #pragma unroll
  for (int mt = 0; mt < 4; ++mt)
    #pragma unroll
    for (int nt = 0; nt < 4; ++nt)
      #pragma unroll
      for (int r = 0; r < 4; ++r) acc[mt][nt][r] = 0.f;

  bf16x8 a[4], an[4], bw[4], bn[4];
  #pragma unroll
  for (int mt = 0; mt < 4; ++mt)
    a[mt] = *reinterpret_cast<const bf16x8*>(
        featSwz + (((size_t)quad * 128 + mtile + mt) * 16 + l16) * 8);
  #pragma unroll
  for (int nt = 0; nt < 4; ++nt)
    bw[nt] = *reinterpret_cast<const bf16x8*>(
        W1Swz + (((size_t)quad * 128 + ntile + nt) * 16 + l16) * 8);

  #pragma unroll
  for (int ks = 0; ks < 32; ++ks) {
    if (ks < 31) {  // prefetch ks+1
      #pragma unroll
      for (int mt = 0; mt < 4; ++mt)
        an[mt] = *reinterpret_cast<const bf16x8*>(
            featSwz + ((((size_t)(ks + 1) * 4 + quad) * 128 + mtile + mt) * 16 + l16) * 8);
      #pragma unroll
      for (int nt = 0; nt < 4; ++nt)
        bn[nt] = *reinterpret_cast<const bf16x8*>(
            W1Swz + ((((size_t)(ks + 1) * 4 + quad) * 128 + ntile + nt) * 16 + l16) * 8);
    }
    #pragma unroll
    for (int mt = 0; mt < 4; ++mt)
      #pragma unroll
      for (int nt = 0; nt < 4; ++nt)
        acc[mt][nt] = __builtin_amdgcn_mfma_f32_16x16x32_bf16(a[mt], bw[nt], acc[mt][nt], 0, 0, 0);
    if (ks < 31) {
      #pragma unroll
      for (int mt = 0; mt < 4; ++mt) a[mt] = an[mt];
      #pragma unroll
      for (int nt = 0; nt < 4; ++nt) bw[nt] = bn[nt];
    }
  }

  // epilogue: tanh fp32, dot with W2, reduce this wave's 64 j-cols
  float c[4][4];
  #pragma unroll
  for (int mt = 0; mt < 4; ++mt)
    #pragma unroll
    for (int r = 0; r < 4; ++r) c[mt][r] = 0.f;

  #pragma unroll
  for (int nt = 0; nt < 4; ++nt) {
    int j = blockIdx.y * 256 + wave * 64 + nt * 16 + l16;
    float bias = b1[j];
    float w2 = W2[j];
    #pragma unroll
    for (int mt = 0; mt < 4; ++mt)
      #pragma unroll
      for (int r = 0; r < 4; ++r) {
        float pre = acc[mt][nt][r] + bias;
        pre = fminf(fmaxf(pre, -15.f), 15.f);
        float ex = __expf(2.f * pre);
        c[mt][r] += w2 * ((ex - 1.f) / (ex + 1.f));
      }
  }
  #pragma unroll
  for (int off = 1; off <= 8; off <<= 1)
    #pragma unroll
    for (int mt = 0; mt < 4; ++mt)
      #pragma unroll
      for (int r = 0; r < 4; ++r)
        c[mt][r] += __shfl_xor(c[mt][r], off);

  if (l16 == 0) {
    int slice = blockIdx.y * 4 + wave;  // 32 slices
    #pragma unroll
    for (int mt = 0; mt < 4; ++mt)
      #pragma unroll
      for (int r = 0; r < 4; ++r) {
        int brow = blockIdx.x * 64 + mt * 16 + quad * 4 + r;
        partial[(size_t)slice * B_SZ + brow] = c[mt][r];
      }
  }
}

// ---- kernel 4: out[b] = b2 + sum over 32 slices of partial[s][b]
__global__ __launch_bounds__(256)
void finalize_kernel(const float* __restrict__ partial, const float* __restrict__ b2,
                     float* __restrict__ out) {
  int b = blockIdx.x * 256 + threadIdx.x;
  float s = b2[0];
  #pragma unroll 8
  for (int i = 0; i < 32; ++i) s += partial[(size_t)i * B_SZ + b];
  out[b] = s;
}

extern "C" void kernel_launch(void* const* d_in, const int* in_sizes, int n_in,
                              void* d_out, int out_size, void* d_ws, size_t ws_size,
                              hipStream_t stream) {
  const float* x1 = (const float*)d_in[0];
  const float* x2 = (const float*)d_in[1];
  const float* Wc = (const float*)d_in[2];
  const float* bc = (const float*)d_in[3];
  const float* W1 = (const float*)d_in[4];
  const float* b1 = (const float*)d_in[5];
  const float* W2 = (const float*)d_in[6];
  const float* b2 = (const float*)d_in[7];

  char* ws = (char*)d_ws;
  unsigned short* WcSwz   = (unsigned short*)(ws);             // 327,680 B
  unsigned short* W1Swz   = (unsigned short*)(ws + 327680);    // 4,194,304 B
  float*          e       = (float*)(ws + 4521984);            // 8,388,608 B
  unsigned short* featSwz = (unsigned short*)(ws + 12910592);  // 4,194,304 B
  float*          partial = (float*)(ws + 17104896);           // 262,144 B
  // total: 17,367,040 B

  {
    int total = C_SZ * NKC + H_SZ * 128;  // 282,624
    convert_kernel<<<(total + 255) / 256, 256, 0, stream>>>(Wc, W1, WcSwz, W1Swz);
  }
  encode_kernel<<<dim3(B_SZ, 2), 256, 0, stream>>>(x1, x2, WcSwz, bc, e);
  feat_kernel<<<(B_SZ * 128 + 255) / 256, 256, 0, stream>>>(e, featSwz);
  fc1_kernel<<<dim3(H_SZ / 64, H_SZ / 256), 256, 0, stream>>>(featSwz, W1Swz, b1, W2, partial);
  finalize_kernel<<<B_SZ / 256, 256, 0, stream>>>(partial, b2, (float*)d_out);
}

// Round 6
// 515.195 us; speedup vs baseline: 1.1189x; 1.1189x over previous
//
#include <hip/hip_runtime.h>

// Model: e = maxpool_L(relu(x @ Wc^T + bc)); feat = [e1-e2, e1*e2];
//        h = tanh(feat @ W1^T + b1); out = h @ W2^T + b2   (all fp32 I/O)
// Sizes: B=2048, L=64, D=300, C=512, H=2048, O=1.
// R5 lesson: MfmaUtil*dur == 35us chip MFMA content in R3/R4/R5 — kernels are
// latency-bound at 2 waves/SIMD (232 regs). Explicit prefetch REGRESSED.
// R6: occupancy attack. encode: N=256/block -> acc[4][4]=64 AGPR, 3 waves/SIMD,
// 3 blocks/CU; n-half-adjacent dispatch for x-tile L2/L3 reuse. fc1: 1024
// blocks, 32x32/wave, acc[2][2] -> 4 waves/SIMD. Loads in-loop (R4 style).

#define B_SZ 2048
#define L_SZ 64
#define D_SZ 300
#define C_SZ 512
#define H_SZ 2048
#define KPAD 320      // D padded to 32
#define NKC 40        // KPAD/8 k-octets (encode)
#define LDSPITCH 328  // x-tile LDS pitch: 2-way bank alias only (free)

typedef __bf16 bf16x8 __attribute__((ext_vector_type(8)));
typedef float f32x4 __attribute__((ext_vector_type(4)));

__device__ __forceinline__ unsigned short f2bf(float f) {
  unsigned int u = __float_as_uint(f);
  u += 0x7fffu + ((u >> 16) & 1u);   // RNE
  return (unsigned short)(u >> 16);
}

// ---- kernel 0: swizzled bf16 weights, k-octet-major / tile / lane16 / 8elem.
// WcSwz[kc<40][ctile<32][l16][8]   (zero-pad k>=300)
// W1Swz[kc<128][jtile<128][l16][8]
__global__ __launch_bounds__(256)
void convert_kernel(const float* __restrict__ Wc, const float* __restrict__ W1,
                    unsigned short* __restrict__ WcSwz, unsigned short* __restrict__ W1Swz) {
  int id = blockIdx.x * 256 + threadIdx.x;
  if (id < C_SZ * NKC) {                      // (c, kc), kc inner
    int c = id / NKC, kc = id - c * NKC;
    unsigned short tmp[8];
    #pragma unroll
    for (int i = 0; i < 8; ++i) {
      int k = kc * 8 + i;
      tmp[i] = (k < D_SZ) ? f2bf(Wc[c * D_SZ + k]) : (unsigned short)0;
    }
    unsigned short* dst = WcSwz + (((kc * 32 + (c >> 4)) * 16) + (c & 15)) * 8;
    *reinterpret_cast<uint4*>(dst) = *reinterpret_cast<uint4*>(tmp);
    return;
  }
  id -= C_SZ * NKC;
  if (id < H_SZ * 128) {                      // (j, kc), kc inner
    int j = id >> 7, kc = id & 127;
    const float* src = W1 + (size_t)j * 1024 + kc * 8;
    unsigned short tmp[8];
    #pragma unroll
    for (int i = 0; i < 8; ++i) tmp[i] = f2bf(src[i]);
    unsigned short* dst = W1Swz + (((kc * 128 + (j >> 4)) * 16) + (j & 15)) * 8;
    *reinterpret_cast<uint4*>(dst) = *reinterpret_cast<uint4*>(tmp);
  }
}

// ---- kernel 1: encode. Block = (n-half, batch, z). M=64, N=256, K=320.
// grid.x = n-half so the two blocks sharing an x-tile dispatch adjacently.
__global__ __launch_bounds__(256, 3)
void encode_kernel(const float* __restrict__ x1, const float* __restrict__ x2,
                   const unsigned short* __restrict__ WcSwz,
                   const float* __restrict__ bc, float* __restrict__ e) {
  const int h = blockIdx.x, b = blockIdx.y, z = blockIdx.z;
  const float* __restrict__ x = (z ? x2 : x1) + (size_t)b * (L_SZ * D_SZ);
  __shared__ unsigned short xs[L_SZ * LDSPITCH];  // 41,984 B -> 3 blocks/CU
  const int tid = threadIdx.x;

  const float4* __restrict__ xv = reinterpret_cast<const float4*>(x);
  for (int i = tid; i < (L_SZ * D_SZ / 4); i += 256) {
    float4 v = xv[i];
    int word = i / 75, col = (i - word * 75) * 4;
    unsigned int lo = (unsigned int)f2bf(v.x) | ((unsigned int)f2bf(v.y) << 16);
    unsigned int hi = (unsigned int)f2bf(v.z) | ((unsigned int)f2bf(v.w) << 16);
    *reinterpret_cast<uint2*>(&xs[word * LDSPITCH + col]) = make_uint2(lo, hi);
  }
  for (int i = tid; i < L_SZ * (KPAD - D_SZ); i += 256) {  // zero K-pad cols
    int word = i / 20, c = D_SZ + (i - word * 20);
    xs[word * LDSPITCH + c] = 0;
  }
  __syncthreads();

  const int wave = tid >> 6, lane = tid & 63;
  const int l16 = lane & 15, quad = lane >> 4;

  f32x4 acc[4][4];
  #pragma unroll
  for (int mt = 0; mt < 4; ++mt)
    #pragma unroll
    for (int nt = 0; nt < 4; ++nt)
      #pragma unroll
      for (int r = 0; r < 4; ++r) acc[mt][nt][r] = 0.f;

  // wave covers ctiles h*16 + wave*4 .. +4 (64 channels)
  #pragma unroll
  for (int ks = 0; ks < KPAD / 32; ++ks) {
    bf16x8 a[4];
    #pragma unroll
    for (int mt = 0; mt < 4; ++mt)
      a[mt] = *reinterpret_cast<const bf16x8*>(&xs[(mt * 16 + l16) * LDSPITCH + ks * 32 + quad * 8]);
    #pragma unroll
    for (int nt = 0; nt < 4; ++nt) {
      int ctile = h * 16 + wave * 4 + nt;
      bf16x8 bw = *reinterpret_cast<const bf16x8*>(
          WcSwz + (((ks * 4 + quad) * 32 + ctile) * 16 + l16) * 8);
      #pragma unroll
      for (int mt = 0; mt < 4; ++mt)
        acc[mt][nt] = __builtin_amdgcn_mfma_f32_16x16x32_bf16(a[mt], bw, acc[mt][nt], 0, 0, 0);
    }
  }

  // +bias, relu, max over the 64 words (C/D: row=quad*4+r, col=l16)
  #pragma unroll
  for (int nt = 0; nt < 4; ++nt) {
    int c = (h * 16 + wave * 4 + nt) * 16 + l16;
    float bias = bc[c];
    float v = 0.f;  // relu floor
    #pragma unroll
    for (int mt = 0; mt < 4; ++mt)
      #pragma unroll
      for (int r = 0; r < 4; ++r)
        v = fmaxf(v, acc[mt][nt][r] + bias);
    v = fmaxf(v, __shfl_xor(v, 16));
    v = fmaxf(v, __shfl_xor(v, 32));
    if (quad == 0)
      e[((size_t)z * B_SZ + b) * C_SZ + c] = v;
  }
}

// ---- kernel 2: featSwz[kc<128][btile<128][l16][8]
__global__ __launch_bounds__(256)
void feat_kernel(const float* __restrict__ e, unsigned short* __restrict__ featSwz) {
  int id = blockIdx.x * 256 + threadIdx.x;   // (b, kc), kc inner
  if (id >= B_SZ * 128) return;
  int b = id >> 7, kc = id & 127;
  unsigned short tmp[8];
  #pragma unroll
  for (int i = 0; i < 8; ++i) {
    int k = kc * 8 + i, c = k & 511;
    float a = e[(size_t)b * C_SZ + c];
    float bb = e[(size_t)B_SZ * C_SZ + (size_t)b * C_SZ + c];
    tmp[i] = f2bf((k < C_SZ) ? (a - bb) : (a * bb));
  }
  unsigned short* dst = featSwz + (((kc * 128 + (b >> 4)) * 16) + (b & 15)) * 8;
  *reinterpret_cast<uint4*>(dst) = *reinterpret_cast<uint4*>(tmp);
}

// ---- kernel 3: fc1+fc2 fused. Block: M=32 x N=128, wave = 32x32, acc[2][2].
// grid (64,16)=1024 blocks -> 4 blocks/CU, 4 waves/SIMD.
// partial[slice<64][b] = sum over this wave's 32 j-cols of tanh(pre)*W2[j].
__global__ __launch_bounds__(256, 4)
void fc1_kernel(const unsigned short* __restrict__ featSwz,
                const unsigned short* __restrict__ W1Swz,
                const float* __restrict__ b1, const float* __restrict__ W2,
                float* __restrict__ partial) {
  const int tid = threadIdx.x;
  const int wave = tid >> 6, lane = tid & 63;
  const int l16 = lane & 15, quad = lane >> 4;
  const int mt0 = blockIdx.x * 2;              // two m-16-tiles
  const int nt0 = blockIdx.y * 8 + wave * 2;   // two n-16-tiles per wave

  f32x4 acc[2][2];
  #pragma unroll
  for (int mt = 0; mt < 2; ++mt)
    #pragma unroll
    for (int nt = 0; nt < 2; ++nt)
      #pragma unroll
      for (int r = 0; r < 4; ++r) acc[mt][nt][r] = 0.f;

  #pragma unroll 4
  for (int ks = 0; ks < 32; ++ks) {
    bf16x8 a[2], bw[2];
    #pragma unroll
    for (int mt = 0; mt < 2; ++mt)
      a[mt] = *reinterpret_cast<const bf16x8*>(
          featSwz + ((((size_t)ks * 4 + quad) * 128 + mt0 + mt) * 16 + l16) * 8);
    #pragma unroll
    for (int nt = 0; nt < 2; ++nt)
      bw[nt] = *reinterpret_cast<const bf16x8*>(
          W1Swz + ((((size_t)ks * 4 + quad) * 128 + nt0 + nt) * 16 + l16) * 8);
    #pragma unroll
    for (int mt = 0; mt < 2; ++mt)
      #pragma unroll
      for (int nt = 0; nt < 2; ++nt)
        acc[mt][nt] = __builtin_amdgcn_mfma_f32_16x16x32_bf16(a[mt], bw[nt], acc[mt][nt], 0, 0, 0);
  }

  // epilogue: tanh fp32, dot with W2, reduce this wave's 32 j-cols
  float c[2][4];
  #pragma unroll
  for (int mt = 0; mt < 2; ++mt)
    #pragma unroll
    for (int r = 0; r < 4; ++r) c[mt][r] = 0.f;

  #pragma unroll
  for (int nt = 0; nt < 2; ++nt) {
    int j = (nt0 + nt) * 16 + l16;
    float bias = b1[j];
    float w2 = W2[j];
    #pragma unroll
    for (int mt = 0; mt < 2; ++mt)
      #pragma unroll
      for (int r = 0; r < 4; ++r) {
        float pre = acc[mt][nt][r] + bias;
        pre = fminf(fmaxf(pre, -15.f), 15.f);
        float ex = __expf(2.f * pre);
        c[mt][r] += w2 * ((ex - 1.f) / (ex + 1.f));
      }
  }
  #pragma unroll
  for (int off = 1; off <= 8; off <<= 1)
    #pragma unroll
    for (int mt = 0; mt < 2; ++mt)
      #pragma unroll
      for (int r = 0; r < 4; ++r)
        c[mt][r] += __shfl_xor(c[mt][r], off);

  if (l16 == 0) {
    int slice = blockIdx.y * 4 + wave;  // 64 slices
    #pragma unroll
    for (int mt = 0; mt < 2; ++mt)
      #pragma unroll
      for (int r = 0; r < 4; ++r) {
        int brow = (mt0 + mt) * 16 + quad * 4 + r;
        partial[(size_t)slice * B_SZ + brow] = c[mt][r];
      }
  }
}

// ---- kernel 4: out[b] = b2 + sum over 64 slices of partial[s][b]
__global__ __launch_bounds__(256)
void finalize_kernel(const float* __restrict__ partial, const float* __restrict__ b2,
                     float* __restrict__ out) {
  int b = blockIdx.x * 256 + threadIdx.x;
  float s = b2[0];
  #pragma unroll 8
  for (int i = 0; i < 64; ++i) s += partial[(size_t)i * B_SZ + b];
  out[b] = s;
}

extern "C" void kernel_launch(void* const* d_in, const int* in_sizes, int n_in,
                              void* d_out, int out_size, void* d_ws, size_t ws_size,
                              hipStream_t stream) {
  const float* x1 = (const float*)d_in[0];
  const float* x2 = (const float*)d_in[1];
  const float* Wc = (const float*)d_in[2];
  const float* bc = (const float*)d_in[3];
  const float* W1 = (const float*)d_in[4];
  const float* b1 = (const float*)d_in[5];
  const float* W2 = (const float*)d_in[6];
  const float* b2 = (const float*)d_in[7];

  char* ws = (char*)d_ws;
  unsigned short* WcSwz   = (unsigned short*)(ws);             // 327,680 B
  unsigned short* W1Swz   = (unsigned short*)(ws + 327680);    // 4,194,304 B
  float*          e       = (float*)(ws + 4521984);            // 8,388,608 B
  unsigned short* featSwz = (unsigned short*)(ws + 12910592);  // 4,194,304 B
  float*          partial = (float*)(ws + 17104896);           // 524,288 B
  // total: 17,629,184 B

  {
    int total = C_SZ * NKC + H_SZ * 128;  // 282,624
    convert_kernel<<<(total + 255) / 256, 256, 0, stream>>>(Wc, W1, WcSwz, W1Swz);
  }
  encode_kernel<<<dim3(2, B_SZ, 2), 256, 0, stream>>>(x1, x2, WcSwz, bc, e);
  feat_kernel<<<(B_SZ * 128 + 255) / 256, 256, 0, stream>>>(e, featSwz);
  fc1_kernel<<<dim3(H_SZ / 32, H_SZ / 128), 256, 0, stream>>>(featSwz, W1Swz, b1, W2, partial);
  finalize_kernel<<<B_SZ / 256, 256, 0, stream>>>(partial, b2, (float*)d_out);
}